// Round 2
// 4459.229 us; speedup vs baseline: 1.1263x; 1.1263x over previous
//
#include <hip/hip_runtime.h>
#include <math.h>

// Adaptive log-softmax NLL, MI355X gfx950.
// Segments: head = weight[0:20000] (+3 cluster cols handled exactly in k_tok),
// tails = weight[20000:40000], [40000:200000], [200000:267735].
// Per segment: blocks own 32-class slices (bf16 in LDS, staged once),
// loop over that cluster's token list, MFMA 16x16x32 bf16, fused exp-sum.
// R0 change (resubmitted in R1 after GPU-acquisition timeout): per-token
// partials go into 128-way REPLICATED accumulators (rep[blockIdx&127][token])
// instead of a single contended array -- the old version serialized ~4.3M
// device-scope atomicAdds into ~40 cache lines (~1 G atomics/s = the whole
// runtime). Final kernel reduces replicas.

#define DIM   1024
#define NTOK  1024
#define NREP  128

typedef __attribute__((ext_vector_type(8))) short short8v;
typedef __attribute__((ext_vector_type(4))) float f32x4;

__device__ __forceinline__ ushort f2bf(float f) {
  union { float f; unsigned u; } v; v.f = f;
  unsigned r = v.u + 0x7fffu + ((v.u >> 16) & 1u);   // RNE
  return (ushort)(r >> 16);
}

// ---- hidden fp32 -> bf16 (2 MB, L2-resident for the GEMMs) ----
__global__ void k_cvt(const float* __restrict__ src, ushort* __restrict__ dst) {
  int t = blockIdx.x * 256 + threadIdx.x;     // 65536 threads * 16 elems
  const float4* s4 = (const float4*)src;
  ushort4* d4 = (ushort4*)dst;
#pragma unroll
  for (int i = 0; i < 4; i++) {
    float4 v = s4[t * 4 + i];
    ushort4 o; o.x = f2bf(v.x); o.y = f2bf(v.y); o.z = f2bf(v.z); o.w = f2bf(v.w);
    d4[t * 4 + i] = o;
  }
}

// ---- zero the replicated accumulators (rep_head || rep_tail, 1 MB contiguous) ----
__global__ void k_zero(float* __restrict__ p) {
  int t = blockIdx.x * 256 + threadIdx.x;     // 65536 threads * float4 = 1 MB
  ((float4*)p)[t] = (float4){0.f, 0.f, 0.f, 0.f};
}

// ---- classify tokens into clusters, build lists ----
__global__ void k_classify(const int* __restrict__ target, int* __restrict__ cid,
                           int* __restrict__ counts, int* __restrict__ lists) {
  int t = threadIdx.x;                 // 1024 threads, 1 block
  if (t < 8) counts[t] = 0;
  __syncthreads();
  int tg = target[t];
  int c = (tg < 20000) ? 0 : (tg < 40000) ? 1 : (tg < 200000) ? 2 : 3;
  cid[t] = c;
  int pos = atomicAdd(&counts[c], 1);
  lists[c * NTOK + pos] = t;
  lists[4 * NTOK + t] = t;             // identity list for the head segment
  if (t == 4) counts[4] = NTOK;        // safe: no atomics touch counts[4]
}

// ---- exact fp32: target logit + 3 cluster-column logits per token ----
__global__ void k_tok(const float* __restrict__ hidden, const float* __restrict__ weight,
                      const float* __restrict__ bias, const float* __restrict__ cw,
                      const float* __restrict__ cbias, const int* __restrict__ target,
                      float* __restrict__ tgt_logit, float* __restrict__ clus_logit,
                      float* __restrict__ head_acc) {
  int n = blockIdx.x;                  // one wave per token
  int L = threadIdx.x;                 // 64 lanes
  int tgt = target[n];
  const float4* h4 = (const float4*)(hidden + (size_t)n * DIM);
  const float4* w4 = (const float4*)(weight + (size_t)tgt * DIM);
  const float4* c0 = (const float4*)(cw);
  const float4* c1 = (const float4*)(cw + DIM);
  const float4* c2 = (const float4*)(cw + 2 * DIM);
  float st = 0.f, s0 = 0.f, s1 = 0.f, s2 = 0.f;
#pragma unroll
  for (int i = 0; i < 4; i++) {
    int idx = L + i * 64;              // 256 float4 per row
    float4 h = h4[idx];
    float4 a = w4[idx]; st += h.x*a.x + h.y*a.y + h.z*a.z + h.w*a.w;
    a = c0[idx];        s0 += h.x*a.x + h.y*a.y + h.z*a.z + h.w*a.w;
    a = c1[idx];        s1 += h.x*a.x + h.y*a.y + h.z*a.z + h.w*a.w;
    a = c2[idx];        s2 += h.x*a.x + h.y*a.y + h.z*a.z + h.w*a.w;
  }
#pragma unroll
  for (int off = 32; off; off >>= 1) {
    st += __shfl_down(st, off); s0 += __shfl_down(s0, off);
    s1 += __shfl_down(s1, off); s2 += __shfl_down(s2, off);
  }
  if (L == 0) {
    st += bias[tgt]; s0 += cbias[0]; s1 += cbias[1]; s2 += cbias[2];
    tgt_logit[n] = st;
    clus_logit[n * 3 + 0] = s0; clus_logit[n * 3 + 1] = s1; clus_logit[n * 3 + 2] = s2;
    head_acc[n] = __expf(s0) + __expf(s1) + __expf(s2);  // 3 cluster cols of head
  }
}

// ---- main fused GEMM + exp-sum ----
// Block: 32-class slice, weight bf16 LDS-resident (64 KB, [oct128][cls32][8]).
// Wave tile: 4 token-groups(16) x 2 class-groups(16); A-frags from global bf16.
// Partials go to rep[blockIdx&(NREP-1)][token] -- low-contention atomics.
__global__ __launch_bounds__(256) void k_gemm(
    const ushort* __restrict__ hidB, const float* __restrict__ wseg,
    const float* __restrict__ bseg, int width,
    const int* __restrict__ list, const int* __restrict__ countp,
    float* __restrict__ rep) {
  __shared__ ushort wlds[32 * 1024];   // 64 KB

  const int tid = threadIdx.x;
  const int cb = blockIdx.x * 32;
  const int rbase = (blockIdx.x & (NREP - 1)) << 10;   // replica row (NTOK=1024)

  // stage weight slice fp32 -> bf16 LDS, K-oct-major: idx = (oct*32+cls)*8+j
  for (int i = tid; i < 8192; i += 256) {
    int row = i >> 8;                  // class within slice
    int f4  = i & 255;                 // float4 index along K
    float4 v = {0.f, 0.f, 0.f, 0.f};
    if (cb + row < width)
      v = ((const float4*)(wseg + (size_t)(cb + row) * DIM))[f4];
    int oct = f4 >> 1;
    int j0  = (f4 & 1) * 4;
    ushort4 o; o.x = f2bf(v.x); o.y = f2bf(v.y); o.z = f2bf(v.z); o.w = f2bf(v.w);
    *(ushort4*)&wlds[oct * 256 + row * 8 + j0] = o;
  }
  __syncthreads();                     // only barrier in the kernel

  const int nT = *countp;
  const int w = tid >> 6;
  const int L = tid & 63;
  const int lane15 = L & 15;
  const int quad = L >> 4;

  float bias_v[2];
#pragma unroll
  for (int cg = 0; cg < 2; cg++) {
    int g = cb + cg * 16 + lane15;
    bias_v[cg] = (g < width) ? bseg[g] : -INFINITY;  // -inf => exp contributes 0
  }
  const int boff0 = quad * 256 + lane15 * 8;

  for (int t0 = 0; t0 < nT; t0 += 256) {
    const ushort* ap[4];
#pragma unroll
    for (int tg = 0; tg < 4; tg++) {
      int pos = t0 + w * 64 + tg * 16 + lane15;
      int r = list[pos < nT ? pos : nT - 1];
      ap[tg] = hidB + (size_t)r * DIM + quad * 8;
    }
    f32x4 acc[4][2];
#pragma unroll
    for (int tg = 0; tg < 4; tg++)
#pragma unroll
      for (int cg = 0; cg < 2; cg++)
        acc[tg][cg] = (f32x4){0.f, 0.f, 0.f, 0.f};

    for (int ks = 0; ks < 32; ks++) {
      short8v a[4], b[2];
#pragma unroll
      for (int tg = 0; tg < 4; tg++)
        a[tg] = *(const short8v*)(ap[tg] + ks * 32);
#pragma unroll
      for (int cg = 0; cg < 2; cg++)
        b[cg] = *(const short8v*)&wlds[ks * 1024 + boff0 + cg * 128];
#pragma unroll
      for (int tg = 0; tg < 4; tg++)
#pragma unroll
        for (int cg = 0; cg < 2; cg++)
          acc[tg][cg] = __builtin_amdgcn_mfma_f32_16x16x32_bf16(
              a[tg], b[cg], acc[tg][cg], 0, 0, 0);
    }

    // epilogue: exp, add bias, reduce 32 classes per token, 1 atomic/token
#pragma unroll
    for (int tg = 0; tg < 4; tg++) {
#pragma unroll
      for (int r = 0; r < 4; r++) {
        float s = __expf(acc[tg][0][r] + bias_v[0]) +
                  __expf(acc[tg][1][r] + bias_v[1]);
        s += __shfl_xor(s, 8);
        s += __shfl_xor(s, 4);
        s += __shfl_xor(s, 2);
        s += __shfl_xor(s, 1);
        if (lane15 == 0) {
          int pos = t0 + w * 64 + tg * 16 + quad * 4 + r;
          if (pos < nT) atomicAdd(&rep[rbase + list[pos]], s);
        }
      }
    }
  }
}

// ---- reduce replicas, assemble nll (head col -i  <->  cluster row 3-i) ----
__global__ void k_final(const float* __restrict__ head_acc,
                        const float* __restrict__ rep_head,
                        const float* __restrict__ rep_tail,
                        const float* __restrict__ tgt_logit,
                        const float* __restrict__ clus_logit,
                        const int* __restrict__ cid, float* __restrict__ out) {
  int n = blockIdx.x * 256 + threadIdx.x;
  if (n >= NTOK) return;
  float hsum = head_acc[n];
  float tsum = 0.f;
  for (int r = 0; r < NREP; r++) {
    hsum += rep_head[r * NTOK + n];    // coalesced across threads
    tsum += rep_tail[r * NTOK + n];
  }
  int c = cid[n];
  float hl = logf(hsum);
  float nll;
  if (c == 0) {
    nll = hl - tgt_logit[n];
  } else {
    float clp = clus_logit[n * 3 + (3 - c)] - hl;
    float tlp = tgt_logit[n] - logf(tsum);
    nll = -(clp + tlp);
  }
  out[n] = nll;
}

extern "C" void kernel_launch(void* const* d_in, const int* in_sizes, int n_in,
                              void* d_out, int out_size, void* d_ws, size_t ws_size,
                              hipStream_t stream) {
  const float* hidden = (const float*)d_in[0];
  const int*   target = (const int*)d_in[1];
  const float* weight = (const float*)d_in[2];
  const float* bias   = (const float*)d_in[3];
  const float* cw     = (const float*)d_in[4];
  const float* cbias  = (const float*)d_in[5];
  float* out = (float*)d_out;

  char* ws = (char*)d_ws;
  ushort* hidB      = (ushort*)ws;                 // 2 MB bf16 hidden
  float* head_acc   = (float*)(ws + 2097152);      // 1024 f32 (base: 3 cluster cols)
  float* tgt_logit  = (float*)(ws + 2101248);      // 1024 f32
  float* clus_logit = (float*)(ws + 2105344);      // 3072 f32
  int*   cid        = (int*)(ws + 2117632);        // 1024 int
  int*   counts     = (int*)(ws + 2121728);        // 8 int
  int*   lists      = (int*)(ws + 2121760);        // 5*1024 int
  float* rep_head   = (float*)(ws + 2142272);      // 128*1024 f32 (512 KB)
  float* rep_tail   = (float*)(ws + 2666560);      // 128*1024 f32 (512 KB)

  k_cvt<<<256, 256, 0, stream>>>(hidden, hidB);
  k_zero<<<256, 256, 0, stream>>>(rep_head);       // zeros rep_head + rep_tail (contiguous 1 MB)
  k_classify<<<1, 1024, 0, stream>>>(target, cid, counts, lists);
  k_tok<<<1024, 64, 0, stream>>>(hidden, weight, bias, cw, cbias, target,
                                 tgt_logit, clus_logit, head_acc);
  // head: classes [0,20000), all tokens (identity list)
  k_gemm<<<625, 256, 0, stream>>>(hidB, weight, bias, 20000,
                                  lists + 4 * NTOK, counts + 4, rep_head);
  // tail 1: [20000,40000)
  k_gemm<<<625, 256, 0, stream>>>(hidB, weight + (size_t)20000 * DIM, bias + 20000,
                                  20000, lists + 1 * NTOK, counts + 1, rep_tail);
  // tail 2: [40000,200000)
  k_gemm<<<5000, 256, 0, stream>>>(hidB, weight + (size_t)40000 * DIM, bias + 40000,
                                   160000, lists + 2 * NTOK, counts + 2, rep_tail);
  // tail 3: [200000,267735)
  k_gemm<<<2117, 256, 0, stream>>>(hidB, weight + (size_t)200000 * DIM, bias + 200000,
                                   67735, lists + 3 * NTOK, counts + 3, rep_tail);
  k_final<<<4, 256, 0, stream>>>(head_acc, rep_head, rep_tail,
                                 tgt_logit, clus_logit, cid, out);
}